// Round 1
// baseline (1357.789 us; speedup 1.0000x reference)
//
#include <hip/hip_runtime.h>

#define NUC 8.0e-4f   // MIU/(U*L) = 1e-6/(0.025*0.05)

struct KP {
  const float *W0,*b0,*W1,*b1,*W2,*b2,*W3,*b3,*W4,*b4,*W5,*b5,*W6,*b6;
  const float *bc1,*bc2,*bc3,*bc4,*bc5,*f1,*inp,*real;
  float *wsBC,*wsDA,*wsF;
};

__device__ __forceinline__ float ftanh(float a){
  float e = __expf(2.0f*a);
  return 1.0f - 2.0f/(e + 1.0f);   // safe at +/-inf
}

__device__ __forceinline__ float wred64(float v){
  #pragma unroll
  for (int off=32; off>0; off>>=1) v += __shfl_down(v, off, 64);
  return v;
}

// ---------------- forward-only kernel: bc1..bc5 + input_data (37000 pts) ----------------
// block: 256 threads, 32 points. thread tile = 4 points x 8 cols.
__global__ __launch_bounds__(256,2) void fwd_kernel(KP P){
  __shared__ float Xs[256][32];        // [feature][point]
  __shared__ float Wt[2][8][256];      // double-buffered K-tile of W
  __shared__ float W6s[256][4];
  __shared__ float b6s[4];
  __shared__ float2 xpt[32];
  __shared__ float redA[4], redB[4];

  const int tid = threadIdx.x;
  const int g0  = blockIdx.x * 32;

  for (int i=tid;i<1024;i+=256) ((float*)W6s)[i] = P.W6[i];
  if (tid<4) b6s[tid] = P.b6[tid];
  if (tid<32){
    int g = g0 + tid;
    float2 xy = make_float2(0.f,0.f);
    if (g < 37000){
      const float* src; int li;
      if      (g <  1000){ src=P.bc1; li=g; }
      else if (g <  2000){ src=P.bc2; li=g-1000; }
      else if (g <  7000){ src=P.bc3; li=g-2000; }
      else if (g < 12000){ src=P.bc4; li=g-7000; }
      else if (g < 17000){ src=P.bc5; li=g-12000; }
      else               { src=P.inp; li=g-17000; }
      xy.x = src[2*li]; xy.y = src[2*li+1];
    }
    xpt[tid] = xy;
  }
  __syncthreads();

  const int rg = tid >> 5;          // 0..7
  const int p0 = rg * 4;            // 4 points per thread
  const int j0 = (tid & 31) * 8;    // 8 cols per thread

  // ---- layer 0 (2 -> 256) ----
  {
    float w0v[8], w1v[8], bv[8];
    *(float4*)&w0v[0] = *(const float4*)(P.W0 + j0);
    *(float4*)&w0v[4] = *(const float4*)(P.W0 + j0 + 4);
    *(float4*)&w1v[0] = *(const float4*)(P.W0 + 256 + j0);
    *(float4*)&w1v[4] = *(const float4*)(P.W0 + 256 + j0 + 4);
    *(float4*)&bv[0]  = *(const float4*)(P.b0 + j0);
    *(float4*)&bv[4]  = *(const float4*)(P.b0 + j0 + 4);
    float tv[4][8];
    #pragma unroll
    for (int pp=0;pp<4;++pp){
      float x0 = xpt[p0+pp].x, x1 = xpt[p0+pp].y;
      #pragma unroll
      for (int jj=0;jj<8;++jj)
        tv[pp][jj] = ftanh(x0*w0v[jj] + x1*w1v[jj] + bv[jj]);
    }
    #pragma unroll
    for (int jj=0;jj<8;++jj)
      *(float4*)&Xs[j0+jj][p0] = make_float4(tv[0][jj],tv[1][jj],tv[2][jj],tv[3][jj]);
  }

  // ---- layers 1..5 (256 -> 256, tanh) ----
  const float* Wl[5] = {P.W1,P.W2,P.W3,P.W4,P.W5};
  const float* bl[5] = {P.b1,P.b2,P.b3,P.b4,P.b5};
  for (int l=0;l<5;++l){
    const float* Wg = Wl[l];
    float acc[4][8];
    #pragma unroll
    for (int pp=0;pp<4;++pp)
      #pragma unroll
      for (int jj=0;jj<8;++jj) acc[pp][jj] = 0.f;

    float4 ra = ((const float4*)Wg)[tid];
    float4 rb = ((const float4*)Wg)[tid+256];
    for (int kt=0; kt<32; ++kt){
      const int buf = kt & 1;
      { float4* dst = (float4*)&Wt[buf][0][0]; dst[tid]=ra; dst[tid+256]=rb; }
      if (kt < 31){
        const float4* src = (const float4*)(Wg + (kt+1)*2048);
        ra = src[tid]; rb = src[tid+256];
      }
      __syncthreads();
      const float4* xp = (const float4*)&Xs[kt*8][p0];   // stride 8 float4 per k
      #pragma unroll
      for (int kk=0;kk<8;++kk){
        float4 xa = xp[kk*8];
        float wv[8];
        *(float4*)&wv[0] = *(const float4*)&Wt[buf][kk][j0];
        *(float4*)&wv[4] = *(const float4*)&Wt[buf][kk][j0+4];
        float xr[4] = {xa.x,xa.y,xa.z,xa.w};
        #pragma unroll
        for (int pp=0;pp<4;++pp)
          #pragma unroll
          for (int jj=0;jj<8;++jj)
            acc[pp][jj] += xr[pp]*wv[jj];
      }
    }
    float bv[8];
    *(float4*)&bv[0] = *(const float4*)(bl[l] + j0);
    *(float4*)&bv[4] = *(const float4*)(bl[l] + j0 + 4);
    __syncthreads();   // all reads of Xs done before overwrite
    float tv[4][8];
    #pragma unroll
    for (int pp=0;pp<4;++pp)
      #pragma unroll
      for (int jj=0;jj<8;++jj)
        tv[pp][jj] = ftanh(acc[pp][jj] + bv[jj]);
    #pragma unroll
    for (int jj=0;jj<8;++jj)
      *(float4*)&Xs[j0+jj][p0] = make_float4(tv[0][jj],tv[1][jj],tv[2][jj],tv[3][jj]);
    __syncthreads();
  }

  // ---- layer 6 (256 -> 4) + per-point MSE contributions ----
  float bcp = 0.f, dap = 0.f;
  if (tid < 128){
    const int p = tid >> 2, j = tid & 3;
    float dot = b6s[j];
    for (int k=0;k<256;++k) dot += Xs[k][p] * W6s[k][j];
    int g = g0 + p;
    if (g < 37000){
      if      (g <  2000){ if (j<3) bcp = dot*dot*(1.0f/1000.f); }
      else if (g <  7000){ if (j<3){ float d = dot - ((j==1)?1.f:0.f); bcp = d*d*(1.0f/5000.f);} }
      else if (g < 12000){ if (j<3) bcp = dot*dot*(1.0f/5000.f); }
      else if (g < 17000){ if (j==3) bcp = dot*dot*(1.0f/5000.f); }
      else { float d = dot - P.real[(g-17000)*4 + j]; dap = d*d*(1.0f/80000.f); }
    }
  }
  bcp = wred64(bcp); dap = wred64(dap);
  const int wv_ = tid >> 6, ln_ = tid & 63;
  if (ln_ == 0){ redA[wv_] = bcp; redB[wv_] = dap; }
  __syncthreads();
  if (tid == 0){
    float sA=0.f, sB=0.f;
    #pragma unroll
    for (int w=0;w<4;++w){ sA += redA[w]; sB += redB[w]; }
    P.wsBC[blockIdx.x] = sA; P.wsDA[blockIdx.x] = sB;
  }
}

// ---------------- PDE kernel: f1 (20000 pts), 5 coupled streams ----------------
// block: 256 threads, 8 points. thread tile = 1 point x 5 streams x 8 cols.
__global__ __launch_bounds__(256,2) void pde_kernel(KP P){
  __shared__ float4 XsA[256][8];   // [feature][point]: (h, dz, dr, dzz)
  __shared__ float  XsB[256][8];   // drr
  __shared__ float  Wt[2][8][256];
  __shared__ float  W6s[256][4];
  __shared__ float  b6s[4];
  __shared__ float2 xpt[8];
  __shared__ float  fin[8][20];
  __shared__ float  red[8];

  const int tid = threadIdx.x;
  const int g0  = blockIdx.x * 8;

  for (int i=tid;i<1024;i+=256) ((float*)W6s)[i] = P.W6[i];
  if (tid<4) b6s[tid] = P.b6[tid];
  if (tid<8){ int g = g0 + tid; xpt[tid] = make_float2(P.f1[2*g], P.f1[2*g+1]); }
  __syncthreads();

  const int p  = tid >> 5;          // 0..7
  const int j0 = (tid & 31) * 8;

  // ---- layer 0: A = x@W0+b0; Dz=W0[0,:], Dr=W0[1,:], Dzz=Drr=0 ----
  {
    float w0v[8], w1v[8], bv[8];
    *(float4*)&w0v[0] = *(const float4*)(P.W0 + j0);
    *(float4*)&w0v[4] = *(const float4*)(P.W0 + j0 + 4);
    *(float4*)&w1v[0] = *(const float4*)(P.W0 + 256 + j0);
    *(float4*)&w1v[4] = *(const float4*)(P.W0 + 256 + j0 + 4);
    *(float4*)&bv[0]  = *(const float4*)(P.b0 + j0);
    *(float4*)&bv[4]  = *(const float4*)(P.b0 + j0 + 4);
    float x0 = xpt[p].x, x1 = xpt[p].y;
    #pragma unroll
    for (int jj=0;jj<8;++jj){
      float a  = x0*w0v[jj] + x1*w1v[jj] + bv[jj];
      float dz = w0v[jj], dr = w1v[jj];
      float t  = ftanh(a);
      float s  = 1.f - t*t;
      float c  = -2.f*t*s;
      XsA[j0+jj][p] = make_float4(t, s*dz, s*dr, c*dz*dz);
      XsB[j0+jj][p] = c*dr*dr;
    }
  }

  // ---- layers 1..5 ----
  const float* Wl[5] = {P.W1,P.W2,P.W3,P.W4,P.W5};
  const float* bl[5] = {P.b1,P.b2,P.b3,P.b4,P.b5};
  for (int l=0;l<5;++l){
    const float* Wg = Wl[l];
    float acc[5][8];
    #pragma unroll
    for (int s=0;s<5;++s)
      #pragma unroll
      for (int jj=0;jj<8;++jj) acc[s][jj] = 0.f;

    float4 ra = ((const float4*)Wg)[tid];
    float4 rb = ((const float4*)Wg)[tid+256];
    for (int kt=0; kt<32; ++kt){
      const int buf = kt & 1;
      { float4* dst = (float4*)&Wt[buf][0][0]; dst[tid]=ra; dst[tid+256]=rb; }
      if (kt < 31){
        const float4* src = (const float4*)(Wg + (kt+1)*2048);
        ra = src[tid]; rb = src[tid+256];
      }
      __syncthreads();
      const float4* xap = ((const float4*)XsA) + kt*64 + p;   // XsA[k][p], stride 8 float4/k
      const float*  xbp = &XsB[kt*8][p];
      #pragma unroll
      for (int kk=0;kk<8;++kk){
        float4 xa = xap[kk*8];
        float  xb = xbp[kk*8];
        float wv[8];
        *(float4*)&wv[0] = *(const float4*)&Wt[buf][kk][j0];
        *(float4*)&wv[4] = *(const float4*)&Wt[buf][kk][j0+4];
        #pragma unroll
        for (int jj=0;jj<8;++jj){
          acc[0][jj] += xa.x*wv[jj];
          acc[1][jj] += xa.y*wv[jj];
          acc[2][jj] += xa.z*wv[jj];
          acc[3][jj] += xa.w*wv[jj];
          acc[4][jj] += xb  *wv[jj];
        }
      }
    }
    float bv[8];
    *(float4*)&bv[0] = *(const float4*)(bl[l] + j0);
    *(float4*)&bv[4] = *(const float4*)(bl[l] + j0 + 4);
    __syncthreads();
    #pragma unroll
    for (int jj=0;jj<8;++jj){
      float a   = acc[0][jj] + bv[jj];
      float Dz  = acc[1][jj], Dr = acc[2][jj], Dzz = acc[3][jj], Drr = acc[4][jj];
      float t   = ftanh(a);
      float s   = 1.f - t*t;
      float c   = -2.f*t*s;
      XsA[j0+jj][p] = make_float4(t, s*Dz, s*Dr, s*Dzz + c*Dz*Dz);
      XsB[j0+jj][p] = s*Drr + c*Dr*Dr;
    }
    __syncthreads();
  }

  // ---- layer 6 (linear) : 5 streams x 4 outputs per point ----
  {
    const int q = tid & 31;
    if (q < 20){
      const int s = q >> 2, j = q & 3;
      const float* basep; int stride;
      if (s < 4){ basep = ((const float*)XsA) + p*4 + s; stride = 32; }
      else      { basep = ((const float*)XsB) + p;       stride = 8;  }
      float dot = (s==0) ? b6s[j] : 0.f;
      for (int k=0;k<256;++k) dot += basep[k*stride] * W6s[k][j];
      fin[p][q] = dot;
    }
  }
  __syncthreads();
  if (tid < 8){
    const float* F = fin[tid];
    float r = xpt[tid].y;
    float uz=F[0],  us=F[1],  ur=F[2];
    float uz_z=F[4],us_z=F[5],ur_z=F[6],p_z=F[7];
    float uz_r=F[8],us_r=F[9],ur_r=F[10],p_r=F[11];
    float uz_zz=F[12],us_zz=F[13],ur_zz=F[14];
    float uz_rr=F[16],us_rr=F[17],ur_rr=F[18];
    float invr = 1.f/r;
    float eq1 = ur*ur_r + uz*ur_z - us*us*invr + p_r
              - NUC*invr*ur_r - NUC*ur_rr - NUC*ur_zz + NUC*ur*invr*invr;
    float eq2 = ur*us_r + uz*us_z + ur*us*invr
              - NUC*invr*us_r - NUC*us_rr - NUC*us_zz + NUC*us*invr*invr;
    float eq3 = ur*uz_r + uz*uz_z + p_z
              - NUC*invr*uz_r - NUC*uz_rr - NUC*uz_zz;
    float eq4 = ur + r*ur_r + r*uz_z;
    red[tid] = (eq1*eq1 + eq2*eq2 + eq3*eq3 + eq4*eq4) * (1.0f/80000.f);
  }
  __syncthreads();
  if (tid == 0){
    float sum = 0.f;
    #pragma unroll
    for (int i=0;i<8;++i) sum += red[i];
    P.wsF[blockIdx.x] = sum;
  }
}

// ---------------- final deterministic reduction ----------------
__global__ void reduce_kernel(const float* wsBC, const float* wsDA, const float* wsF,
                              float* out, int nbF, int nbP){
  __shared__ float sm[256];
  const int tid = threadIdx.x;
  float a;

  a = 0.f; for (int i=tid;i<nbF;i+=256) a += wsBC[i];
  sm[tid]=a; __syncthreads();
  for (int off=128; off>0; off>>=1){ if (tid<off) sm[tid]+=sm[tid+off]; __syncthreads(); }
  if (tid==0) out[0]=sm[0];
  __syncthreads();

  a = 0.f; for (int i=tid;i<nbF;i+=256) a += wsDA[i];
  sm[tid]=a; __syncthreads();
  for (int off=128; off>0; off>>=1){ if (tid<off) sm[tid]+=sm[tid+off]; __syncthreads(); }
  if (tid==0) out[1]=sm[0];
  __syncthreads();

  a = 0.f; for (int i=tid;i<nbP;i+=256) a += wsF[i];
  sm[tid]=a; __syncthreads();
  for (int off=128; off>0; off>>=1){ if (tid<off) sm[tid]+=sm[tid+off]; __syncthreads(); }
  if (tid==0) out[2]=sm[0];
}

extern "C" void kernel_launch(void* const* d_in, const int* in_sizes, int n_in,
                              void* d_out, int out_size, void* d_ws, size_t ws_size,
                              hipStream_t stream){
  KP P;
  P.W0=(const float*)d_in[0];  P.b0=(const float*)d_in[1];
  P.W1=(const float*)d_in[2];  P.b1=(const float*)d_in[3];
  P.W2=(const float*)d_in[4];  P.b2=(const float*)d_in[5];
  P.W3=(const float*)d_in[6];  P.b3=(const float*)d_in[7];
  P.W4=(const float*)d_in[8];  P.b4=(const float*)d_in[9];
  P.W5=(const float*)d_in[10]; P.b5=(const float*)d_in[11];
  P.W6=(const float*)d_in[12]; P.b6=(const float*)d_in[13];
  P.bc1=(const float*)d_in[14]; P.bc2=(const float*)d_in[15];
  P.bc3=(const float*)d_in[16]; P.bc4=(const float*)d_in[17];
  P.bc5=(const float*)d_in[18]; P.f1=(const float*)d_in[19];
  P.inp=(const float*)d_in[20]; P.real=(const float*)d_in[21];
  float* ws = (float*)d_ws;
  P.wsBC = ws; P.wsDA = ws + 2048; P.wsF = ws + 4096;

  const int nbF = (37000 + 31) / 32;   // 1157
  const int nbP = 20000 / 8;           // 2500
  fwd_kernel<<<dim3(nbF), dim3(256), 0, stream>>>(P);
  pde_kernel<<<dim3(nbP), dim3(256), 0, stream>>>(P);
  reduce_kernel<<<dim3(1), dim3(256), 0, stream>>>(P.wsBC, P.wsDA, P.wsF, (float*)d_out, nbF, nbP);
}

// Round 2
// 1214.316 us; speedup vs baseline: 1.1182x; 1.1182x over previous
//
#include <hip/hip_runtime.h>

#define NUC 8.0e-4f   // MIU/(U*L) = 1e-6/(0.025*0.05)

struct KP {
  const float *W0,*b0,*W1,*b1,*W2,*b2,*W3,*b3,*W4,*b4,*W5,*b5,*W6,*b6;
  const float *bc1,*bc2,*bc3,*bc4,*bc5,*f1,*inp,*real;
  float *wsBC,*wsDA,*wsF;
};

__device__ __forceinline__ float ftanh(float a){
  float e = __expf(2.0f*a);
  return 1.0f - 2.0f/(e + 1.0f);   // safe at +/-inf
}

__device__ __forceinline__ float wred64(float v){
  #pragma unroll
  for (int off=32; off>0; off>>=1) v += __shfl_down(v, off, 64);
  return v;
}

// ---------------- forward-only kernel: bc1..bc5 + input_data (37000 pts) ----------------
// block: 256 threads = 4 waves; wave w: points w*8..w*8+7, lane owns cols 4*lane..4*lane+3.
__global__ __launch_bounds__(256,3) void fwd_kernel(KP P){
  __shared__ float  Xs[32][256];     // [pt][k]  32KB, point-major
  __shared__ float  Wt[2][4][256];   // 8KB, KT=4 double-buffered
  __shared__ float  W6s[256][4];     // 4KB
  __shared__ float2 xpt[32];
  __shared__ float  redA[4], redB[4];

  const int tid = threadIdx.x;
  const int g0  = blockIdx.x * 32;

  for (int i=tid;i<1024;i+=256) ((float*)W6s)[i] = P.W6[i];
  if (tid<32){
    int g = g0 + tid;
    float2 xy = make_float2(0.f,0.f);
    if (g < 37000){
      const float* src; int li;
      if      (g <  1000){ src=P.bc1; li=g; }
      else if (g <  2000){ src=P.bc2; li=g-1000; }
      else if (g <  7000){ src=P.bc3; li=g-2000; }
      else if (g < 12000){ src=P.bc4; li=g-7000; }
      else if (g < 17000){ src=P.bc5; li=g-12000; }
      else               { src=P.inp; li=g-17000; }
      xy.x = src[2*li]; xy.y = src[2*li+1];
    }
    xpt[tid] = xy;
  }
  __syncthreads();

  const int lane = tid & 63;
  const int c0   = lane * 4;          // 4 cols per lane, wave covers 256
  const int p0   = (tid >> 6) * 8;    // 8 points per wave

  // ---- layer 0 (2 -> 256) ----
  {
    float4 w0 = *(const float4*)(P.W0 + c0);
    float4 w1 = *(const float4*)(P.W0 + 256 + c0);
    float4 bv = *(const float4*)(P.b0 + c0);
    #pragma unroll
    for (int i=0;i<8;++i){
      float x0 = xpt[p0+i].x, x1 = xpt[p0+i].y;
      float4 t;
      t.x = ftanh(x0*w0.x + x1*w1.x + bv.x);
      t.y = ftanh(x0*w0.y + x1*w1.y + bv.y);
      t.z = ftanh(x0*w0.z + x1*w1.z + bv.z);
      t.w = ftanh(x0*w0.w + x1*w1.w + bv.w);
      *(float4*)&Xs[p0+i][c0] = t;
    }
  }
  __syncthreads();

  // ---- layers 1..5 (256 -> 256, tanh) ----
  const float* Wl[5] = {P.W1,P.W2,P.W3,P.W4,P.W5};
  const float* bl[5] = {P.b1,P.b2,P.b3,P.b4,P.b5};
  for (int l=0;l<5;++l){
    const float* Wg = Wl[l];
    float acc[8][4];
    #pragma unroll
    for (int i=0;i<8;++i){ acc[i][0]=0.f; acc[i][1]=0.f; acc[i][2]=0.f; acc[i][3]=0.f; }

    float4 ra = ((const float4*)Wg)[tid];           // rows 0..3
    for (int kt=0; kt<64; ++kt){
      const int buf = kt & 1;
      ((float4*)(&Wt[buf][0][0]))[tid] = ra;
      if (kt < 63) ra = ((const float4*)(Wg + (kt+1)*1024))[tid];
      __syncthreads();
      float4 xv[8];
      #pragma unroll
      for (int i=0;i<8;++i) xv[i] = *(const float4*)&Xs[p0+i][kt*4];
      #pragma unroll
      for (int kk=0;kk<4;++kk){
        float4 wv = *(const float4*)&Wt[buf][kk][c0];
        #pragma unroll
        for (int i=0;i<8;++i){
          float x = ((const float*)&xv[i])[kk];
          acc[i][0] += x*wv.x; acc[i][1] += x*wv.y;
          acc[i][2] += x*wv.z; acc[i][3] += x*wv.w;
        }
      }
    }
    float4 bv = *(const float4*)(bl[l] + c0);
    __syncthreads();    // all waves done reading Xs/Wt
    #pragma unroll
    for (int i=0;i<8;++i){
      float4 t;
      t.x = ftanh(acc[i][0] + bv.x);
      t.y = ftanh(acc[i][1] + bv.y);
      t.z = ftanh(acc[i][2] + bv.z);
      t.w = ftanh(acc[i][3] + bv.w);
      *(float4*)&Xs[p0+i][c0] = t;
    }
  }
  __syncthreads();

  // ---- layer 6 (256 -> 4) + per-point MSE contributions ----
  float bcp = 0.f, dap = 0.f;
  if (tid < 128){
    const int pp = tid >> 2, j = tid & 3;
    float dot = P.b6[j];
    const int k0 = pp;                    // stagger: distinct banks per point
    for (int it=0; it<256; ++it){
      int k = (k0 + it) & 255;
      dot += Xs[pp][k] * W6s[k][j];
    }
    int g = g0 + pp;
    if (g < 37000){
      if      (g <  2000){ if (j<3) bcp = dot*dot*(1.0f/1000.f); }
      else if (g <  7000){ if (j<3){ float d = dot - ((j==1)?1.f:0.f); bcp = d*d*(1.0f/5000.f);} }
      else if (g < 12000){ if (j<3) bcp = dot*dot*(1.0f/5000.f); }
      else if (g < 17000){ if (j==3) bcp = dot*dot*(1.0f/5000.f); }
      else { float d = dot - P.real[(g-17000)*4 + j]; dap = d*d*(1.0f/80000.f); }
    }
  }
  bcp = wred64(bcp); dap = wred64(dap);
  const int wv_ = tid >> 6, ln_ = tid & 63;
  if (ln_ == 0){ redA[wv_] = bcp; redB[wv_] = dap; }
  __syncthreads();
  if (tid == 0){
    float sA=0.f, sB=0.f;
    #pragma unroll
    for (int w=0;w<4;++w){ sA += redA[w]; sB += redB[w]; }
    P.wsBC[blockIdx.x] = sA; P.wsDA[blockIdx.x] = sB;
  }
}

// ---------------- PDE kernel: f1 (20000 pts), 5 coupled streams ----------------
// block: 256 threads = 4 waves; wave w: points 2w,2w+1; lane owns cols 4*lane..4*lane+3.
__global__ __launch_bounds__(256,3) void pde_kernel(KP P){
  __shared__ float  Xp[8][5][256];   // [pt][stream][k]  40KB  (h,dz,dr,dzz,drr)
  __shared__ float  Wt[2][4][256];   // 8KB
  __shared__ float2 xpt[8];
  __shared__ float  fin[8][20];
  __shared__ float  red[8];

  const int tid = threadIdx.x;
  const int g0  = blockIdx.x * 8;

  if (tid<8){ int g = g0 + tid; xpt[tid] = make_float2(P.f1[2*g], P.f1[2*g+1]); }
  __syncthreads();

  const int lane = tid & 63;
  const int c0   = lane * 4;
  const int p0   = (tid >> 6) * 2;    // 2 points per wave

  // ---- layer 0 ----
  {
    float4 w0 = *(const float4*)(P.W0 + c0);
    float4 w1 = *(const float4*)(P.W0 + 256 + c0);
    float4 bv = *(const float4*)(P.b0 + c0);
    float wz[4] = {w0.x,w0.y,w0.z,w0.w};
    float wr[4] = {w1.x,w1.y,w1.z,w1.w};
    float bb[4] = {bv.x,bv.y,bv.z,bv.w};
    #pragma unroll
    for (int pp=0;pp<2;++pp){
      float x0 = xpt[p0+pp].x, x1 = xpt[p0+pp].y;
      float o[5][4];
      #pragma unroll
      for (int c=0;c<4;++c){
        float a = x0*wz[c] + x1*wr[c] + bb[c];
        float t = ftanh(a), s = 1.f - t*t, cc = -2.f*t*s;
        o[0][c]=t; o[1][c]=s*wz[c]; o[2][c]=s*wr[c];
        o[3][c]=cc*wz[c]*wz[c]; o[4][c]=cc*wr[c]*wr[c];
      }
      #pragma unroll
      for (int s=0;s<5;++s)
        *(float4*)&Xp[p0+pp][s][c0] = make_float4(o[s][0],o[s][1],o[s][2],o[s][3]);
    }
  }
  __syncthreads();

  // ---- layers 1..5 ----
  const float* Wl[5] = {P.W1,P.W2,P.W3,P.W4,P.W5};
  const float* bl[5] = {P.b1,P.b2,P.b3,P.b4,P.b5};
  for (int l=0;l<5;++l){
    const float* Wg = Wl[l];
    float acc[2][5][4];
    #pragma unroll
    for (int pp=0;pp<2;++pp)
      #pragma unroll
      for (int s=0;s<5;++s)
        #pragma unroll
        for (int c=0;c<4;++c) acc[pp][s][c] = 0.f;

    float4 ra = ((const float4*)Wg)[tid];
    for (int kt=0; kt<64; ++kt){
      const int buf = kt & 1;
      ((float4*)(&Wt[buf][0][0]))[tid] = ra;
      if (kt < 63) ra = ((const float4*)(Wg + (kt+1)*1024))[tid];
      __syncthreads();
      float4 xv[2][5];
      #pragma unroll
      for (int pp=0;pp<2;++pp)
        #pragma unroll
        for (int s=0;s<5;++s)
          xv[pp][s] = *(const float4*)&Xp[p0+pp][s][kt*4];
      #pragma unroll
      for (int kk=0;kk<4;++kk){
        float4 wv = *(const float4*)&Wt[buf][kk][c0];
        #pragma unroll
        for (int pp=0;pp<2;++pp){
          #pragma unroll
          for (int s=0;s<5;++s){
            float x = ((const float*)&xv[pp][s])[kk];
            acc[pp][s][0] += x*wv.x; acc[pp][s][1] += x*wv.y;
            acc[pp][s][2] += x*wv.z; acc[pp][s][3] += x*wv.w;
          }
        }
      }
    }
    float4 bv = *(const float4*)(bl[l] + c0);
    float bb[4] = {bv.x,bv.y,bv.z,bv.w};
    __syncthreads();    // all waves done reading Xp/Wt
    #pragma unroll
    for (int pp=0;pp<2;++pp){
      float o[5][4];
      #pragma unroll
      for (int c=0;c<4;++c){
        float a   = acc[pp][0][c] + bb[c];
        float Dz  = acc[pp][1][c], Dr = acc[pp][2][c];
        float Dzz = acc[pp][3][c], Drr = acc[pp][4][c];
        float t = ftanh(a), s = 1.f - t*t, cc = -2.f*t*s;
        o[0][c]=t; o[1][c]=s*Dz; o[2][c]=s*Dr;
        o[3][c]=s*Dzz + cc*Dz*Dz; o[4][c]=s*Drr + cc*Dr*Dr;
      }
      #pragma unroll
      for (int s=0;s<5;++s)
        *(float4*)&Xp[p0+pp][s][c0] = make_float4(o[s][0],o[s][1],o[s][2],o[s][3]);
    }
  }
  __syncthreads();

  // ---- layer 6 (linear): 8 pts x 5 streams x 4 outs ----
  {
    const int p = tid >> 5;
    const int q = tid & 31;
    if (q < 20){
      const int s = q >> 2, j = q & 3;
      const float* xrow = &Xp[p][s][0];
      float dot = (s==0) ? P.b6[j] : 0.f;
      const int k0 = tid & 63;             // stride-1 stagger -> 2-way max
      for (int it=0; it<256; ++it){
        int k = (k0 + it) & 255;
        dot += xrow[k] * P.W6[4*k + j];
      }
      fin[p][q] = dot;
    }
  }
  __syncthreads();
  if (tid < 8){
    const float* F = fin[tid];
    float r = xpt[tid].y;
    float uz=F[0],  us=F[1],  ur=F[2];
    float uz_z=F[4],us_z=F[5],ur_z=F[6],p_z=F[7];
    float uz_r=F[8],us_r=F[9],ur_r=F[10],p_r=F[11];
    float uz_zz=F[12],us_zz=F[13],ur_zz=F[14];
    float uz_rr=F[16],us_rr=F[17],ur_rr=F[18];
    float invr = 1.f/r;
    float eq1 = ur*ur_r + uz*ur_z - us*us*invr + p_r
              - NUC*invr*ur_r - NUC*ur_rr - NUC*ur_zz + NUC*ur*invr*invr;
    float eq2 = ur*us_r + uz*us_z + ur*us*invr
              - NUC*invr*us_r - NUC*us_rr - NUC*us_zz + NUC*us*invr*invr;
    float eq3 = ur*uz_r + uz*uz_z + p_z
              - NUC*invr*uz_r - NUC*uz_rr - NUC*uz_zz;
    float eq4 = ur + r*ur_r + r*uz_z;
    red[tid] = (eq1*eq1 + eq2*eq2 + eq3*eq3 + eq4*eq4) * (1.0f/80000.f);
  }
  __syncthreads();
  if (tid == 0){
    float sum = 0.f;
    #pragma unroll
    for (int i=0;i<8;++i) sum += red[i];
    P.wsF[blockIdx.x] = sum;
  }
}

// ---------------- final deterministic reduction ----------------
__global__ void reduce_kernel(const float* wsBC, const float* wsDA, const float* wsF,
                              float* out, int nbF, int nbP){
  __shared__ float sm[256];
  const int tid = threadIdx.x;
  float a;

  a = 0.f; for (int i=tid;i<nbF;i+=256) a += wsBC[i];
  sm[tid]=a; __syncthreads();
  for (int off=128; off>0; off>>=1){ if (tid<off) sm[tid]+=sm[tid+off]; __syncthreads(); }
  if (tid==0) out[0]=sm[0];
  __syncthreads();

  a = 0.f; for (int i=tid;i<nbF;i+=256) a += wsDA[i];
  sm[tid]=a; __syncthreads();
  for (int off=128; off>0; off>>=1){ if (tid<off) sm[tid]+=sm[tid+off]; __syncthreads(); }
  if (tid==0) out[1]=sm[0];
  __syncthreads();

  a = 0.f; for (int i=tid;i<nbP;i+=256) a += wsF[i];
  sm[tid]=a; __syncthreads();
  for (int off=128; off>0; off>>=1){ if (tid<off) sm[tid]+=sm[tid+off]; __syncthreads(); }
  if (tid==0) out[2]=sm[0];
}

extern "C" void kernel_launch(void* const* d_in, const int* in_sizes, int n_in,
                              void* d_out, int out_size, void* d_ws, size_t ws_size,
                              hipStream_t stream){
  KP P;
  P.W0=(const float*)d_in[0];  P.b0=(const float*)d_in[1];
  P.W1=(const float*)d_in[2];  P.b1=(const float*)d_in[3];
  P.W2=(const float*)d_in[4];  P.b2=(const float*)d_in[5];
  P.W3=(const float*)d_in[6];  P.b3=(const float*)d_in[7];
  P.W4=(const float*)d_in[8];  P.b4=(const float*)d_in[9];
  P.W5=(const float*)d_in[10]; P.b5=(const float*)d_in[11];
  P.W6=(const float*)d_in[12]; P.b6=(const float*)d_in[13];
  P.bc1=(const float*)d_in[14]; P.bc2=(const float*)d_in[15];
  P.bc3=(const float*)d_in[16]; P.bc4=(const float*)d_in[17];
  P.bc5=(const float*)d_in[18]; P.f1=(const float*)d_in[19];
  P.inp=(const float*)d_in[20]; P.real=(const float*)d_in[21];
  float* ws = (float*)d_ws;
  P.wsBC = ws; P.wsDA = ws + 2048; P.wsF = ws + 4096;

  const int nbF = (37000 + 31) / 32;   // 1157
  const int nbP = 20000 / 8;           // 2500
  fwd_kernel<<<dim3(nbF), dim3(256), 0, stream>>>(P);
  pde_kernel<<<dim3(nbP), dim3(256), 0, stream>>>(P);
  reduce_kernel<<<dim3(1), dim3(256), 0, stream>>>(P.wsBC, P.wsDA, P.wsF, (float*)d_out, nbF, nbP);
}